// Round 1
// baseline (217.353 us; speedup 1.0000x reference)
//
#include <hip/hip_runtime.h>

// ---------------------------------------------------------------------------
// RelationNetwork: B=32, C=256, N=64 (8x8), D_G_IN=514, HG=HF=512, D_OUT=256
//
// Decomposition:
//   layer0 is linear in [x_q, x_p, rel(p,q)]  (rel.mean()==0 exactly), so
//     h0[b,p,q,h] = relu( U'[b,q,h] + V'[b,p,h] )
//   with U'[b,q,h] = sum_c x[b,c,q] W0[c,h]       - oh(q)W0[512,h] - ow(q)W0[513,h]
//        V'[b,p,h] = sum_c x[b,c,p] W0[256+c,h]   + oh(p)W0[512,h] + ow(p)W0[513,h] + b0[h]
//   Then per (b,p) tile of 64 pair-rows (q=0..63):
//     h1 = relu(h0 @ W1 + b1)        (bf16 MFMA 32x32x16)
//     rel = relu(h1 @ W2 + b2)       -> column-sums only (never materialized)
//   embedding[b,:] = sum over p-tiles of column sums; then tiny f-MLP.
// ---------------------------------------------------------------------------

typedef short short8 __attribute__((ext_vector_type(8)));
typedef float f32x16 __attribute__((ext_vector_type(16)));

__device__ __forceinline__ unsigned short f2bf(float f) {
    unsigned u = __builtin_bit_cast(unsigned, f);
    u = (u + 0x7FFFu + ((u >> 16) & 1u)) >> 16;   // RNE
    return (unsigned short)u;
}

// ---------------------------------------------------------------------------
// Kernel 1: per-object linear terms U', V'  (x: [32,256,64] fp32)
// grid: 256 blocks (b = blk>>3, n0 = (blk&7)*8), 512 threads (h = tid)
// ---------------------------------------------------------------------------
__global__ __launch_bounds__(512) void uv_kernel(
    const float* __restrict__ x, const float* __restrict__ W0,
    const float* __restrict__ b0, float* __restrict__ Up, float* __restrict__ Vp)
{
    __shared__ float xs[256 * 8];
    const int blk = blockIdx.x;
    const int b = blk >> 3, n0 = (blk & 7) * 8;
    const int tid = threadIdx.x;

    for (int i = tid; i < 2048; i += 512) {
        int c = i >> 3, r = i & 7;
        xs[i] = x[((size_t)b * 256 + c) * 64 + n0 + r];
    }
    __syncthreads();

    const int h = tid;
    float ua[8], va[8];
#pragma unroll
    for (int r = 0; r < 8; ++r) { ua[r] = 0.f; va[r] = 0.f; }

    for (int c = 0; c < 256; ++c) {
        float wa = W0[(size_t)c * 512 + h];
        float wb = W0[(size_t)(256 + c) * 512 + h];
#pragma unroll
        for (int r = 0; r < 8; ++r) {
            float xv = xs[c * 8 + r];
            ua[r] += xv * wa;
            va[r] += xv * wb;
        }
    }
    const float w2a = W0[(size_t)512 * 512 + h];
    const float w2b = W0[(size_t)513 * 512 + h];
    const float bb = b0[h];
#pragma unroll
    for (int r = 0; r < 8; ++r) {
        int n = n0 + r;
        float fh = (float)(n >> 3), fw = (float)(n & 7);
        Up[((size_t)b * 64 + n) * 512 + h] = ua[r] - fh * w2a - fw * w2b;
        Vp[((size_t)b * 64 + n) * 512 + h] = va[r] + fh * w2a + fw * w2b + bb;
    }
}

// ---------------------------------------------------------------------------
// Kernel 2: convert W1,W2 to bf16 in MFMA-fragment order.
// chunk idx = (kg)*512 + col, kg = k/8 (k = kg*8 + j), 8 bf16 (16B) per chunk.
// grid: 256 x 256 (gid 0..65535; gid>>15 selects W1/W2)
// ---------------------------------------------------------------------------
__global__ __launch_bounds__(256) void wswz_kernel(
    const float* __restrict__ W1, const float* __restrict__ W2,
    unsigned short* __restrict__ W1s, unsigned short* __restrict__ W2s)
{
    int gid = blockIdx.x * 256 + threadIdx.x;
    int m = gid >> 15;
    int idx = gid & 32767;            // kg*512 + col
    int col = idx & 511;
    int kg = idx >> 9;                // 0..63
    const float* W = m ? W2 : W1;
    unsigned short* O = m ? W2s : W1s;
    short8 v;
#pragma unroll
    for (int j = 0; j < 8; ++j)
        v[j] = (short)f2bf(W[(size_t)(kg * 8 + j) * 512 + col]);
    *(short8*)(O + (size_t)idx * 8) = v;
}

// ---------------------------------------------------------------------------
// Kernel 3: fused main kernel. One block per (b,p): 64 pair-rows (q), HG=512.
// 512 threads = 8 waves; wave w owns cols [w*64, w*64+64).
// LDS: single 64KB buffer holds h0, then (after barrier) h1. XOR swizzle
// byte ^= (row&15)<<4 on all LDS accesses (kills the stride-1024B conflict).
// ---------------------------------------------------------------------------
__global__ __launch_bounds__(512, 4) void main_kernel(
    const float* __restrict__ Up, const float* __restrict__ Vp,
    const unsigned short* __restrict__ W1s, const unsigned short* __restrict__ W2s,
    const float* __restrict__ b1, const float* __restrict__ b2,
    float* __restrict__ partials)
{
    __shared__ __align__(16) unsigned char lds[64 * 1024];

    const int blk = blockIdx.x;             // b*64 + p
    const int b = blk >> 6, p = blk & 63;
    const int tid = threadIdx.x;
    const int lane = tid & 63, wave = tid >> 6;
    const int l31 = lane & 31, lg = lane >> 5;
    const int swz = (l31 & 15) << 4;
    const int wcol = wave * 64;

    // ---- build h0[q][h] = relu(U'[b,q,h] + V'[b,p,h]), bf16, swizzled ----
    {
        const int cc = tid & 63;            // col-chunk of 8
        const int r0 = tid >> 6;            // 0..7
        const float* vb = Vp + ((size_t)(b * 64 + p)) * 512 + cc * 8;
        float4 v0 = *(const float4*)(vb);
        float4 v1 = *(const float4*)(vb + 4);
#pragma unroll
        for (int it = 0; it < 8; ++it) {
            int row = r0 + it * 8;          // q
            const float* ub = Up + ((size_t)(b * 64 + row)) * 512 + cc * 8;
            float4 u0 = *(const float4*)(ub);
            float4 u1 = *(const float4*)(ub + 4);
            short8 hv;
            hv[0] = (short)f2bf(fmaxf(u0.x + v0.x, 0.f));
            hv[1] = (short)f2bf(fmaxf(u0.y + v0.y, 0.f));
            hv[2] = (short)f2bf(fmaxf(u0.z + v0.z, 0.f));
            hv[3] = (short)f2bf(fmaxf(u0.w + v0.w, 0.f));
            hv[4] = (short)f2bf(fmaxf(u1.x + v1.x, 0.f));
            hv[5] = (short)f2bf(fmaxf(u1.y + v1.y, 0.f));
            hv[6] = (short)f2bf(fmaxf(u1.z + v1.z, 0.f));
            hv[7] = (short)f2bf(fmaxf(u1.w + v1.w, 0.f));
            int off = row * 1024 + ((cc * 16) ^ ((row & 15) << 4));
            *(short8*)(&lds[off]) = hv;
        }
    }
    __syncthreads();

    // ---- GEMM1: acc = h0 @ W1 (wave cols wcol..wcol+63) ----
    f32x16 acc[2][2];
#pragma unroll
    for (int i = 0; i < 2; ++i)
#pragma unroll
        for (int j = 0; j < 2; ++j) acc[i][j] = (f32x16)0.f;

    const int arow0 = l31 * 1024;
    const int arow1 = (l31 + 32) * 1024;

#pragma unroll 2
    for (int ks = 0; ks < 32; ++ks) {
        int achunk = (ks * 32 + lg * 16) ^ swz;
        short8 a0 = *(const short8*)(&lds[arow0 + achunk]);
        short8 a1 = *(const short8*)(&lds[arow1 + achunk]);
        const unsigned short* bp = W1s + ((size_t)((ks * 2 + lg) * 512 + wcol + l31)) * 8;
        short8 bv0 = *(const short8*)(bp);
        short8 bv1 = *(const short8*)(bp + 32 * 8);
        acc[0][0] = __builtin_amdgcn_mfma_f32_32x32x16_bf16(a0, bv0, acc[0][0], 0, 0, 0);
        acc[1][0] = __builtin_amdgcn_mfma_f32_32x32x16_bf16(a1, bv0, acc[1][0], 0, 0, 0);
        acc[0][1] = __builtin_amdgcn_mfma_f32_32x32x16_bf16(a0, bv1, acc[0][1], 0, 0, 0);
        acc[1][1] = __builtin_amdgcn_mfma_f32_32x32x16_bf16(a1, bv1, acc[1][1], 0, 0, 0);
    }
    __syncthreads();   // everyone done READING h0

    // ---- h1 = relu(acc + b1) -> bf16 into same LDS (swizzled) ----
    {
        float bias0 = b1[wcol + l31];
        float bias1 = b1[wcol + 32 + l31];
#pragma unroll
        for (int cf = 0; cf < 2; ++cf) {
            int col = wcol + cf * 32 + l31;
            float bias = cf ? bias1 : bias0;
#pragma unroll
            for (int rf = 0; rf < 2; ++rf) {
#pragma unroll
                for (int reg = 0; reg < 16; ++reg) {
                    int row = rf * 32 + (reg & 3) + 8 * (reg >> 2) + 4 * lg;
                    float v = fmaxf(acc[rf][cf][reg] + bias, 0.f);
                    int off = row * 1024 + ((col * 2) ^ ((row & 15) << 4));
                    *(unsigned short*)(&lds[off]) = f2bf(v);
                }
            }
        }
    }
    __syncthreads();   // h1 complete

    // ---- GEMM2: acc2 = h1 @ W2 ----
    f32x16 acc2[2][2];
#pragma unroll
    for (int i = 0; i < 2; ++i)
#pragma unroll
        for (int j = 0; j < 2; ++j) acc2[i][j] = (f32x16)0.f;

#pragma unroll 2
    for (int ks = 0; ks < 32; ++ks) {
        int achunk = (ks * 32 + lg * 16) ^ swz;
        short8 a0 = *(const short8*)(&lds[arow0 + achunk]);
        short8 a1 = *(const short8*)(&lds[arow1 + achunk]);
        const unsigned short* bp = W2s + ((size_t)((ks * 2 + lg) * 512 + wcol + l31)) * 8;
        short8 bv0 = *(const short8*)(bp);
        short8 bv1 = *(const short8*)(bp + 32 * 8);
        acc2[0][0] = __builtin_amdgcn_mfma_f32_32x32x16_bf16(a0, bv0, acc2[0][0], 0, 0, 0);
        acc2[1][0] = __builtin_amdgcn_mfma_f32_32x32x16_bf16(a1, bv0, acc2[1][0], 0, 0, 0);
        acc2[0][1] = __builtin_amdgcn_mfma_f32_32x32x16_bf16(a0, bv1, acc2[0][1], 0, 0, 0);
        acc2[1][1] = __builtin_amdgcn_mfma_f32_32x32x16_bf16(a1, bv1, acc2[1][1], 0, 0, 0);
    }

    // ---- relations = relu(acc2 + b2); column-sum over the 64 pair-rows ----
    {
        float s[2];
#pragma unroll
        for (int cf = 0; cf < 2; ++cf) {
            int col = wcol + cf * 32 + l31;
            float bias = b2[col];
            float t = 0.f;
#pragma unroll
            for (int rf = 0; rf < 2; ++rf)
#pragma unroll
                for (int reg = 0; reg < 16; ++reg)
                    t += fmaxf(acc2[rf][cf][reg] + bias, 0.f);
            t += __shfl_xor(t, 32);          // combine the two row-halves
            s[cf] = t;
        }
        if (lane < 32) {
            partials[(size_t)blk * 512 + wcol + lane] = s[0];
            partials[(size_t)blk * 512 + wcol + 32 + lane] = s[1];
        }
    }
}

// ---------------------------------------------------------------------------
// Kernel 4: embedding[b,col] = sum_p partials[(b*64+p)*512 + col]
// ---------------------------------------------------------------------------
__global__ __launch_bounds__(256) void reduce_kernel(
    const float* __restrict__ partials, float* __restrict__ emb)
{
    int o = blockIdx.x * 256 + threadIdx.x;     // 0..16383
    int b = o >> 9, col = o & 511;
    const float* ptr = partials + ((size_t)b * 64) * 512 + col;
    float s = 0.f;
#pragma unroll 8
    for (int i = 0; i < 64; ++i) s += ptr[(size_t)i * 512];
    emb[o] = s;
}

// ---------------------------------------------------------------------------
// Kernel 5: f-MLP: out = relu(emb @ fW0 + fb0) @ fW1 + fb1
// ---------------------------------------------------------------------------
__global__ __launch_bounds__(256) void f_kernel(
    const float* __restrict__ emb, const float* __restrict__ fW0,
    const float* __restrict__ fb0, const float* __restrict__ fW1,
    const float* __restrict__ fb1, float* __restrict__ out)
{
    __shared__ float es[512];
    __shared__ float hs[512];
    const int b = blockIdx.x, tid = threadIdx.x;
    es[tid] = emb[b * 512 + tid];
    es[tid + 256] = emb[b * 512 + 256 + tid];
    __syncthreads();
    float a0 = fb0[tid], a1 = fb0[tid + 256];
    for (int c = 0; c < 512; ++c) {
        float e = es[c];
        a0 += e * fW0[(size_t)c * 512 + tid];
        a1 += e * fW0[(size_t)c * 512 + tid + 256];
    }
    hs[tid] = fmaxf(a0, 0.f);
    hs[tid + 256] = fmaxf(a1, 0.f);
    __syncthreads();
    float o = fb1[tid];
    for (int c = 0; c < 512; ++c) o += hs[c] * fW1[(size_t)c * 256 + tid];
    out[b * 256 + tid] = o;
}

// ---------------------------------------------------------------------------
extern "C" void kernel_launch(void* const* d_in, const int* in_sizes, int n_in,
                              void* d_out, int out_size, void* d_ws, size_t ws_size,
                              hipStream_t stream)
{
    const float* x   = (const float*)d_in[0];
    const float* gW0 = (const float*)d_in[1];
    const float* gb0 = (const float*)d_in[2];
    const float* gW1 = (const float*)d_in[3];
    const float* gb1 = (const float*)d_in[4];
    const float* gW2 = (const float*)d_in[5];
    const float* gb2 = (const float*)d_in[6];
    const float* fW0 = (const float*)d_in[7];
    const float* fb0 = (const float*)d_in[8];
    const float* fW1 = (const float*)d_in[9];
    const float* fb1 = (const float*)d_in[10];
    float* out = (float*)d_out;

    char* ws = (char*)d_ws;
    float* Up              = (float*)(ws);                              // 4 MB
    float* Vp              = (float*)(ws + (4  << 20));                 // 4 MB
    unsigned short* W1s    = (unsigned short*)(ws + (8 << 20));         // 512 KB
    unsigned short* W2s    = (unsigned short*)(ws + (8 << 20) + (512 << 10)); // 512 KB
    float* partials        = (float*)(ws + (9  << 20));                 // 4 MB
    float* emb             = (float*)(ws + (13 << 20));                 // 64 KB

    uv_kernel<<<256, 512, 0, stream>>>(x, gW0, gb0, Up, Vp);
    wswz_kernel<<<256, 256, 0, stream>>>(gW1, gW2, W1s, W2s);
    main_kernel<<<2048, 512, 0, stream>>>(Up, Vp, W1s, W2s, gb1, gb2, partials);
    reduce_kernel<<<64, 256, 0, stream>>>(partials, emb);
    f_kernel<<<32, 256, 0, stream>>>(emb, fW0, fb0, fW1, fb1, out);
}

// Round 2
// 212.751 us; speedup vs baseline: 1.0216x; 1.0216x over previous
//
#include <hip/hip_runtime.h>

// ---------------------------------------------------------------------------
// RelationNetwork: B=32, C=256, N=64 (8x8), D_G_IN=514, HG=HF=512, D_OUT=256
//
//   h0[b,p,q,h] = relu( U'[b,q,h] + V'[b,p,h] )      (layer0 is linear in concat)
//   per (b,p) block:  h1 = relu(h0 @ W1 + b1); colsum(relu(h1 @ W2 + b2))
//   GEMM1 is operand-swapped: D1[h,q] so consecutive acc regs = consecutive h
//   -> h1 epilogue packs with v_cvt_pk_bf16_f32 and writes ds_write_b64.
// ---------------------------------------------------------------------------

typedef short short8 __attribute__((ext_vector_type(8)));
typedef float f32x16 __attribute__((ext_vector_type(16)));

__device__ __forceinline__ unsigned short f2bf(float f) {
    unsigned u = __builtin_bit_cast(unsigned, f);
    u = (u + 0x7FFFu + ((u >> 16) & 1u)) >> 16;   // RNE
    return (unsigned short)u;
}

// pack two f32 -> u32 of 2 bf16 (lo = a, hi = b) in one instruction
__device__ __forceinline__ unsigned cvt_pk(float a, float b) {
    unsigned r;
    asm("v_cvt_pk_bf16_f32 %0, %1, %2" : "=v"(r) : "v"(a), "v"(b));
    return r;
}

// ---------------------------------------------------------------------------
// Kernel 1: per-object linear terms U', V'  (x: [32,256,64] fp32)
// grid: 256 blocks (b = blk>>3, n0 = (blk&7)*8), 512 threads (h = tid)
// ---------------------------------------------------------------------------
__global__ __launch_bounds__(512) void uv_kernel(
    const float* __restrict__ x, const float* __restrict__ W0,
    const float* __restrict__ b0, float* __restrict__ Up, float* __restrict__ Vp)
{
    __shared__ float xs[256 * 8];
    const int blk = blockIdx.x;
    const int b = blk >> 3, n0 = (blk & 7) * 8;
    const int tid = threadIdx.x;

    for (int i = tid; i < 2048; i += 512) {
        int c = i >> 3, r = i & 7;
        xs[i] = x[((size_t)b * 256 + c) * 64 + n0 + r];
    }
    __syncthreads();

    const int h = tid;
    float ua[8], va[8];
#pragma unroll
    for (int r = 0; r < 8; ++r) { ua[r] = 0.f; va[r] = 0.f; }

    for (int c = 0; c < 256; ++c) {
        float wa = W0[(size_t)c * 512 + h];
        float wb = W0[(size_t)(256 + c) * 512 + h];
#pragma unroll
        for (int r = 0; r < 8; ++r) {
            float xv = xs[c * 8 + r];
            ua[r] += xv * wa;
            va[r] += xv * wb;
        }
    }
    const float w2a = W0[(size_t)512 * 512 + h];
    const float w2b = W0[(size_t)513 * 512 + h];
    const float bb = b0[h];
#pragma unroll
    for (int r = 0; r < 8; ++r) {
        int n = n0 + r;
        float fh = (float)(n >> 3), fw = (float)(n & 7);
        Up[((size_t)b * 64 + n) * 512 + h] = ua[r] - fh * w2a - fw * w2b;
        Vp[((size_t)b * 64 + n) * 512 + h] = va[r] + fh * w2a + fw * w2b + bb;
    }
}

// ---------------------------------------------------------------------------
// Kernel 2: convert W1,W2 to bf16 in MFMA-fragment order.
// chunk idx = kg*512 + col; 8 bf16 = W[kg*8 + j][col], j=0..7.
// (This order serves BOTH the A-role (swapped GEMM1) and B-role (GEMM2):
//  each is "8 consecutive k at a fixed row/col index".)
// ---------------------------------------------------------------------------
__global__ __launch_bounds__(256) void wswz_kernel(
    const float* __restrict__ W1, const float* __restrict__ W2,
    unsigned short* __restrict__ W1s, unsigned short* __restrict__ W2s)
{
    int gid = blockIdx.x * 256 + threadIdx.x;
    int m = gid >> 15;
    int idx = gid & 32767;            // kg*512 + col
    int col = idx & 511;
    int kg = idx >> 9;                // 0..63
    const float* W = m ? W2 : W1;
    unsigned short* O = m ? W2s : W1s;
    short8 v;
#pragma unroll
    for (int j = 0; j < 8; ++j)
        v[j] = (short)f2bf(W[(size_t)(kg * 8 + j) * 512 + col]);
    *(short8*)(O + (size_t)idx * 8) = v;
}

// ---------------------------------------------------------------------------
// Kernel 3: fused main kernel. One block per (b,p): 64 pair-rows (q), HG=512.
// 512 threads = 8 waves; wave w owns h-cols [w*64, w*64+64).
// LDS: single 64KB buffer holds h0, then (after barriers) h1, layout
// [64 rows][512 cols] bf16, XOR swizzle byte ^= (row&15)<<4.
// ---------------------------------------------------------------------------
__global__ __launch_bounds__(512, 4) void main_kernel(
    const float* __restrict__ Up, const float* __restrict__ Vp,
    const unsigned short* __restrict__ W1s, const unsigned short* __restrict__ W2s,
    const float* __restrict__ b1, const float* __restrict__ b2,
    float* __restrict__ partials)
{
    __shared__ __align__(16) unsigned char lds[64 * 1024];

    const int blk = blockIdx.x;             // b*64 + p
    const int b = blk >> 6, p = blk & 63;
    const int tid = threadIdx.x;
    const int lane = tid & 63, wave = tid >> 6;
    const int l31 = lane & 31, lg = lane >> 5;
    const int swz = (l31 & 15) << 4;
    const int wcol = wave * 64;

    // ---- build h0[q][h] = relu(U'[b,q,h] + V'[b,p,h]), bf16, swizzled ----
    {
        const int cc = tid & 63;            // col-chunk of 8
        const int r0 = tid >> 6;            // 0..7
        const float* vb = Vp + ((size_t)(b * 64 + p)) * 512 + cc * 8;
        float4 v0 = *(const float4*)(vb);
        float4 v1 = *(const float4*)(vb + 4);
#pragma unroll
        for (int it = 0; it < 8; ++it) {
            int row = r0 + it * 8;          // q
            const float* ub = Up + ((size_t)(b * 64 + row)) * 512 + cc * 8;
            float4 u0 = *(const float4*)(ub);
            float4 u1 = *(const float4*)(ub + 4);
            uint4 w;
            w.x = cvt_pk(fmaxf(u0.x + v0.x, 0.f), fmaxf(u0.y + v0.y, 0.f));
            w.y = cvt_pk(fmaxf(u0.z + v0.z, 0.f), fmaxf(u0.w + v0.w, 0.f));
            w.z = cvt_pk(fmaxf(u1.x + v1.x, 0.f), fmaxf(u1.y + v1.y, 0.f));
            w.w = cvt_pk(fmaxf(u1.z + v1.z, 0.f), fmaxf(u1.w + v1.w, 0.f));
            int off = row * 1024 + ((cc * 16) ^ ((row & 15) << 4));
            *(uint4*)(&lds[off]) = w;
        }
    }
    __syncthreads();

    // ---- GEMM1 (swapped): acc[hf][qf] = D1[h, q], h = wave cols ----
    f32x16 acc[2][2];
#pragma unroll
    for (int i = 0; i < 2; ++i)
#pragma unroll
        for (int j = 0; j < 2; ++j) acc[i][j] = (f32x16)0.f;

    const int arow0 = l31 * 1024;             // q = l31       (B-frag col)
    const int arow1 = (l31 + 32) * 1024;      // q = l31 + 32

    __builtin_amdgcn_s_setprio(1);
#pragma unroll 2
    for (int ks = 0; ks < 32; ++ks) {
        int achunk = (ks * 32 + lg * 16) ^ swz;
        short8 h0q0 = *(const short8*)(&lds[arow0 + achunk]);
        short8 h0q1 = *(const short8*)(&lds[arow1 + achunk]);
        const unsigned short* bp = W1s + ((size_t)((ks * 2 + lg) * 512 + wcol + l31)) * 8;
        short8 wv0 = *(const short8*)(bp);            // A rows h = wcol..+31
        short8 wv1 = *(const short8*)(bp + 32 * 8);   // A rows h = wcol+32..+63
        acc[0][0] = __builtin_amdgcn_mfma_f32_32x32x16_bf16(wv0, h0q0, acc[0][0], 0, 0, 0);
        acc[1][0] = __builtin_amdgcn_mfma_f32_32x32x16_bf16(wv1, h0q0, acc[1][0], 0, 0, 0);
        acc[0][1] = __builtin_amdgcn_mfma_f32_32x32x16_bf16(wv0, h0q1, acc[0][1], 0, 0, 0);
        acc[1][1] = __builtin_amdgcn_mfma_f32_32x32x16_bf16(wv1, h0q1, acc[1][1], 0, 0, 0);
    }
    __builtin_amdgcn_s_setprio(0);
    __syncthreads();   // everyone done READING h0

    // ---- h1 = relu(acc + b1) -> bf16 into same LDS (swizzled) ----
    // acc[hf][qf] reg r: h = wcol + hf*32 + (r&3) + 8*(r>>2) + 4*lg,
    //                    q = qf*32 + l31.  Reg-quads are 4 consecutive h.
    {
#pragma unroll
        for (int hf = 0; hf < 2; ++hf) {
#pragma unroll
            for (int g = 0; g < 4; ++g) {
                int h = wcol + hf * 32 + g * 8 + 4 * lg;
                float4 bb = *(const float4*)(b1 + h);
#pragma unroll
                for (int qf = 0; qf < 2; ++qf) {
                    int q = qf * 32 + l31;
                    float a0 = fmaxf(acc[hf][qf][g * 4 + 0] + bb.x, 0.f);
                    float a1 = fmaxf(acc[hf][qf][g * 4 + 1] + bb.y, 0.f);
                    float a2 = fmaxf(acc[hf][qf][g * 4 + 2] + bb.z, 0.f);
                    float a3 = fmaxf(acc[hf][qf][g * 4 + 3] + bb.w, 0.f);
                    uint2 pk;
                    pk.x = cvt_pk(a0, a1);
                    pk.y = cvt_pk(a2, a3);
                    int off = q * 1024 + ((h * 2) ^ ((q & 15) << 4));
                    *(uint2*)(&lds[off]) = pk;       // ds_write_b64
                }
            }
        }
    }
    __syncthreads();   // h1 complete

    // ---- GEMM2 (normal): acc2[rf][cf] = D2[q, h2] ----
    f32x16 acc2[2][2];
#pragma unroll
    for (int i = 0; i < 2; ++i)
#pragma unroll
        for (int j = 0; j < 2; ++j) acc2[i][j] = (f32x16)0.f;

    __builtin_amdgcn_s_setprio(1);
#pragma unroll 2
    for (int ks = 0; ks < 32; ++ks) {
        int achunk = (ks * 32 + lg * 16) ^ swz;
        short8 a0 = *(const short8*)(&lds[arow0 + achunk]);   // h1[q=l31, k..]
        short8 a1 = *(const short8*)(&lds[arow1 + achunk]);   // h1[q=l31+32, k..]
        const unsigned short* bp = W2s + ((size_t)((ks * 2 + lg) * 512 + wcol + l31)) * 8;
        short8 bv0 = *(const short8*)(bp);
        short8 bv1 = *(const short8*)(bp + 32 * 8);
        acc2[0][0] = __builtin_amdgcn_mfma_f32_32x32x16_bf16(a0, bv0, acc2[0][0], 0, 0, 0);
        acc2[1][0] = __builtin_amdgcn_mfma_f32_32x32x16_bf16(a1, bv0, acc2[1][0], 0, 0, 0);
        acc2[0][1] = __builtin_amdgcn_mfma_f32_32x32x16_bf16(a0, bv1, acc2[0][1], 0, 0, 0);
        acc2[1][1] = __builtin_amdgcn_mfma_f32_32x32x16_bf16(a1, bv1, acc2[1][1], 0, 0, 0);
    }
    __builtin_amdgcn_s_setprio(0);

    // ---- relations = relu(acc2 + b2); column-sum over the 64 pair-rows ----
    {
        float s[2];
#pragma unroll
        for (int cf = 0; cf < 2; ++cf) {
            int col = wcol + cf * 32 + l31;
            float bias = b2[col];
            float t = 0.f;
#pragma unroll
            for (int rf = 0; rf < 2; ++rf)
#pragma unroll
                for (int reg = 0; reg < 16; ++reg)
                    t += fmaxf(acc2[rf][cf][reg] + bias, 0.f);
            t += __shfl_xor(t, 32);          // combine the two row-halves
            s[cf] = t;
        }
        if (lane < 32) {
            partials[(size_t)blk * 512 + wcol + lane] = s[0];
            partials[(size_t)blk * 512 + wcol + 32 + lane] = s[1];
        }
    }
}

// ---------------------------------------------------------------------------
// Kernel 4: embedding reduce + f-MLP fused. One block per b (32 x 256).
// ---------------------------------------------------------------------------
__global__ __launch_bounds__(256) void reduce_f_kernel(
    const float* __restrict__ partials,
    const float* __restrict__ fW0, const float* __restrict__ fb0,
    const float* __restrict__ fW1, const float* __restrict__ fb1,
    float* __restrict__ out)
{
    __shared__ float es[512];
    __shared__ float hs[512];
    const int b = blockIdx.x, tid = threadIdx.x;

    float s0 = 0.f, s1 = 0.f;
    const float* base = partials + (size_t)b * 64 * 512;
#pragma unroll 8
    for (int p = 0; p < 64; ++p) {
        s0 += base[(size_t)p * 512 + tid];
        s1 += base[(size_t)p * 512 + tid + 256];
    }
    es[tid] = s0;
    es[tid + 256] = s1;
    __syncthreads();

    float a0 = fb0[tid], a1 = fb0[tid + 256];
    for (int c = 0; c < 512; ++c) {
        float e = es[c];
        a0 += e * fW0[(size_t)c * 512 + tid];
        a1 += e * fW0[(size_t)c * 512 + tid + 256];
    }
    hs[tid] = fmaxf(a0, 0.f);
    hs[tid + 256] = fmaxf(a1, 0.f);
    __syncthreads();

    float o = fb1[tid];
    for (int c = 0; c < 512; ++c) o += hs[c] * fW1[(size_t)c * 256 + tid];
    out[b * 256 + tid] = o;
}

// ---------------------------------------------------------------------------
extern "C" void kernel_launch(void* const* d_in, const int* in_sizes, int n_in,
                              void* d_out, int out_size, void* d_ws, size_t ws_size,
                              hipStream_t stream)
{
    const float* x   = (const float*)d_in[0];
    const float* gW0 = (const float*)d_in[1];
    const float* gb0 = (const float*)d_in[2];
    const float* gW1 = (const float*)d_in[3];
    const float* gb1 = (const float*)d_in[4];
    const float* gW2 = (const float*)d_in[5];
    const float* gb2 = (const float*)d_in[6];
    const float* fW0 = (const float*)d_in[7];
    const float* fb0 = (const float*)d_in[8];
    const float* fW1 = (const float*)d_in[9];
    const float* fb1 = (const float*)d_in[10];
    float* out = (float*)d_out;

    char* ws = (char*)d_ws;
    float* Up              = (float*)(ws);                              // 4 MB
    float* Vp              = (float*)(ws + (4  << 20));                 // 4 MB
    unsigned short* W1s    = (unsigned short*)(ws + (8 << 20));         // 512 KB
    unsigned short* W2s    = (unsigned short*)(ws + (8 << 20) + (512 << 10)); // 512 KB
    float* partials        = (float*)(ws + (9  << 20));                 // 4 MB

    uv_kernel<<<256, 512, 0, stream>>>(x, gW0, gb0, Up, Vp);
    wswz_kernel<<<256, 256, 0, stream>>>(gW1, gW2, W1s, W2s);
    main_kernel<<<2048, 512, 0, stream>>>(Up, Vp, W1s, W2s, gb1, gb2, partials);
    reduce_f_kernel<<<32, 256, 0, stream>>>(partials, fW0, fb0, fW1, fb1, out);
}

// Round 3
// 177.760 us; speedup vs baseline: 1.2227x; 1.1968x over previous
//
#include <hip/hip_runtime.h>

// ---------------------------------------------------------------------------
// RelationNetwork: B=32, C=256, N=64 (8x8), D_G_IN=514, HG=HF=512, D_OUT=256
//
//   h0[b,p,q,h] = relu( U'[b,q,h] + V'[b,p,h] )      (layer0 linear in concat)
//   Block = (b, p-pair): builds TWO 64x512 h0 tiles (shared U reads), runs
//   both through GEMM1/GEMM2 sharing each weight fragment across 8 MFMAs
//   (halves L2 weight traffic vs 1 tile/block). Column sums -> atomicAdd emb.
//   f-MLP as two wide GEMV kernels.
// ---------------------------------------------------------------------------

typedef short short8 __attribute__((ext_vector_type(8)));
typedef float f32x16 __attribute__((ext_vector_type(16)));

__device__ __forceinline__ unsigned short f2bf(float f) {
    unsigned u = __builtin_bit_cast(unsigned, f);
    u = (u + 0x7FFFu + ((u >> 16) & 1u)) >> 16;   // RNE
    return (unsigned short)u;
}

__device__ __forceinline__ unsigned cvt_pk(float a, float b) {
    unsigned r;
    asm("v_cvt_pk_bf16_f32 %0, %1, %2" : "=v"(r) : "v"(a), "v"(b));
    return r;
}

// ---------------------------------------------------------------------------
// Kernel 1: per-object linear terms U', V'
// ---------------------------------------------------------------------------
__global__ __launch_bounds__(512) void uv_kernel(
    const float* __restrict__ x, const float* __restrict__ W0,
    const float* __restrict__ b0, float* __restrict__ Up, float* __restrict__ Vp)
{
    __shared__ float xs[256 * 8];
    const int blk = blockIdx.x;
    const int b = blk >> 3, n0 = (blk & 7) * 8;
    const int tid = threadIdx.x;

    for (int i = tid; i < 2048; i += 512) {
        int c = i >> 3, r = i & 7;
        xs[i] = x[((size_t)b * 256 + c) * 64 + n0 + r];
    }
    __syncthreads();

    const int h = tid;
    float ua[8], va[8];
#pragma unroll
    for (int r = 0; r < 8; ++r) { ua[r] = 0.f; va[r] = 0.f; }

    for (int c = 0; c < 256; ++c) {
        float wa = W0[(size_t)c * 512 + h];
        float wb = W0[(size_t)(256 + c) * 512 + h];
#pragma unroll
        for (int r = 0; r < 8; ++r) {
            float xv = xs[c * 8 + r];
            ua[r] += xv * wa;
            va[r] += xv * wb;
        }
    }
    const float w2a = W0[(size_t)512 * 512 + h];
    const float w2b = W0[(size_t)513 * 512 + h];
    const float bb = b0[h];
#pragma unroll
    for (int r = 0; r < 8; ++r) {
        int n = n0 + r;
        float fh = (float)(n >> 3), fw = (float)(n & 7);
        Up[((size_t)b * 64 + n) * 512 + h] = ua[r] - fh * w2a - fw * w2b;
        Vp[((size_t)b * 64 + n) * 512 + h] = va[r] + fh * w2a + fw * w2b + bb;
    }
}

// ---------------------------------------------------------------------------
// Kernel 2: W1,W2 -> bf16 fragment order (kg*512+col, 8 k's per chunk),
// plus zero emb (graph-safe re-init every call; runs before main_kernel).
// ---------------------------------------------------------------------------
__global__ __launch_bounds__(256) void wswz_kernel(
    const float* __restrict__ W1, const float* __restrict__ W2,
    unsigned short* __restrict__ W1s, unsigned short* __restrict__ W2s,
    float* __restrict__ emb)
{
    int gid = blockIdx.x * 256 + threadIdx.x;
    if (gid < 16384) emb[gid] = 0.f;
    int m = gid >> 15;
    int idx = gid & 32767;            // kg*512 + col
    int col = idx & 511;
    int kg = idx >> 9;                // 0..63
    const float* W = m ? W2 : W1;
    unsigned short* O = m ? W2s : W1s;
    short8 v;
#pragma unroll
    for (int j = 0; j < 8; ++j)
        v[j] = (short)f2bf(W[(size_t)(kg * 8 + j) * 512 + col]);
    *(short8*)(O + (size_t)idx * 8) = v;
}

// ---------------------------------------------------------------------------
// Kernel 3: fused main kernel, TWO p-tiles per block.
// 1024 blocks = (b, pp) via chunked XCD swizzle; 512 threads = 8 waves;
// wave w owns h-cols [w*64, w*64+64) for BOTH tiles.
// Dynamic LDS 128KB: T0 [64][512] bf16 swizzled + T1. Swizzle: byte ^= (q&15)<<4.
// ---------------------------------------------------------------------------
__global__ __launch_bounds__(512, 2) void main_kernel(
    const float* __restrict__ Up, const float* __restrict__ Vp,
    const unsigned short* __restrict__ W1s, const unsigned short* __restrict__ W2s,
    const float* __restrict__ b1, const float* __restrict__ b2,
    float* __restrict__ emb)
{
    extern __shared__ __align__(16) unsigned char lds[];
    unsigned char* T[2] = { lds, lds + 65536 };

    // chunked bijective XCD swizzle: 1024 wgs, 128 per XCD
    const int wg = ((blockIdx.x & 7) << 7) | (blockIdx.x >> 3);
    const int b = wg >> 5, pp = wg & 31;
    const int p0 = pp * 2, p1 = p0 + 1;

    const int tid = threadIdx.x;
    const int lane = tid & 63, wave = tid >> 6;
    const int l31 = lane & 31, lg = lane >> 5;
    const int swz = (l31 & 15) << 4;
    const int wcol = wave * 64;

    // ---- build h0 tiles: T0 = relu(U+V[p0]), T1 = relu(U+V[p1]) ----
    {
        const int cc = tid & 63;            // col-chunk of 8 (== lane)
        const int r0 = tid >> 6;            // == wave
        const float* vA = Vp + ((size_t)(b * 64 + p0)) * 512 + cc * 8;
        const float* vB = Vp + ((size_t)(b * 64 + p1)) * 512 + cc * 8;
        float4 vA0 = *(const float4*)(vA),     vA1 = *(const float4*)(vA + 4);
        float4 vB0 = *(const float4*)(vB),     vB1 = *(const float4*)(vB + 4);
#pragma unroll
        for (int it = 0; it < 8; ++it) {
            int row = r0 + it * 8;          // q
            const float* ub = Up + ((size_t)(b * 64 + row)) * 512 + cc * 8;
            float4 u0 = *(const float4*)(ub);
            float4 u1 = *(const float4*)(ub + 4);
            int off = row * 1024 + ((cc * 16) ^ ((row & 15) << 4));
            uint4 w;
            w.x = cvt_pk(fmaxf(u0.x + vA0.x, 0.f), fmaxf(u0.y + vA0.y, 0.f));
            w.y = cvt_pk(fmaxf(u0.z + vA0.z, 0.f), fmaxf(u0.w + vA0.w, 0.f));
            w.z = cvt_pk(fmaxf(u1.x + vA1.x, 0.f), fmaxf(u1.y + vA1.y, 0.f));
            w.w = cvt_pk(fmaxf(u1.z + vA1.z, 0.f), fmaxf(u1.w + vA1.w, 0.f));
            *(uint4*)(&T[0][off]) = w;
            w.x = cvt_pk(fmaxf(u0.x + vB0.x, 0.f), fmaxf(u0.y + vB0.y, 0.f));
            w.y = cvt_pk(fmaxf(u0.z + vB0.z, 0.f), fmaxf(u0.w + vB0.w, 0.f));
            w.z = cvt_pk(fmaxf(u1.x + vB1.x, 0.f), fmaxf(u1.y + vB1.y, 0.f));
            w.w = cvt_pk(fmaxf(u1.z + vB1.z, 0.f), fmaxf(u1.w + vB1.w, 0.f));
            *(uint4*)(&T[1][off]) = w;
        }
    }
    __syncthreads();

    const int arow0 = l31 * 1024;
    const int arow1 = (l31 + 32) * 1024;

    // ---- GEMM1 (swapped): acc[t][hf][qf] = D1[h, q] for tile t ----
    f32x16 acc[2][2][2];
#pragma unroll
    for (int t = 0; t < 2; ++t)
#pragma unroll
        for (int i = 0; i < 2; ++i)
#pragma unroll
            for (int j = 0; j < 2; ++j) acc[t][i][j] = (f32x16)0.f;

    __builtin_amdgcn_s_setprio(1);
#pragma unroll 2
    for (int ks = 0; ks < 32; ++ks) {
        int achunk = (ks * 32 + lg * 16) ^ swz;
        short8 a00 = *(const short8*)(&T[0][arow0 + achunk]);
        short8 a01 = *(const short8*)(&T[0][arow1 + achunk]);
        short8 a10 = *(const short8*)(&T[1][arow0 + achunk]);
        short8 a11 = *(const short8*)(&T[1][arow1 + achunk]);
        const unsigned short* bp = W1s + ((size_t)((ks * 2 + lg) * 512 + wcol + l31)) * 8;
        short8 wv0 = *(const short8*)(bp);            // h rows wcol..+31
        short8 wv1 = *(const short8*)(bp + 32 * 8);   // h rows wcol+32..+63
        acc[0][0][0] = __builtin_amdgcn_mfma_f32_32x32x16_bf16(wv0, a00, acc[0][0][0], 0, 0, 0);
        acc[0][1][0] = __builtin_amdgcn_mfma_f32_32x32x16_bf16(wv1, a00, acc[0][1][0], 0, 0, 0);
        acc[0][0][1] = __builtin_amdgcn_mfma_f32_32x32x16_bf16(wv0, a01, acc[0][0][1], 0, 0, 0);
        acc[0][1][1] = __builtin_amdgcn_mfma_f32_32x32x16_bf16(wv1, a01, acc[0][1][1], 0, 0, 0);
        acc[1][0][0] = __builtin_amdgcn_mfma_f32_32x32x16_bf16(wv0, a10, acc[1][0][0], 0, 0, 0);
        acc[1][1][0] = __builtin_amdgcn_mfma_f32_32x32x16_bf16(wv1, a10, acc[1][1][0], 0, 0, 0);
        acc[1][0][1] = __builtin_amdgcn_mfma_f32_32x32x16_bf16(wv0, a11, acc[1][0][1], 0, 0, 0);
        acc[1][1][1] = __builtin_amdgcn_mfma_f32_32x32x16_bf16(wv1, a11, acc[1][1][1], 0, 0, 0);
    }
    __builtin_amdgcn_s_setprio(0);
    __syncthreads();   // all waves done READING h0

    // ---- h1 = relu(acc + b1) -> bf16 back into T0/T1 ----
    // acc[t][hf][qf] reg r: h = wcol + hf*32 + (r&3) + 8*(r>>2) + 4*lg, q = qf*32 + l31
    {
#pragma unroll
        for (int hf = 0; hf < 2; ++hf) {
#pragma unroll
            for (int g = 0; g < 4; ++g) {
                int h = wcol + hf * 32 + g * 8 + 4 * lg;
                float4 bb = *(const float4*)(b1 + h);
#pragma unroll
                for (int t = 0; t < 2; ++t) {
#pragma unroll
                    for (int qf = 0; qf < 2; ++qf) {
                        int q = qf * 32 + l31;
                        float a0 = fmaxf(acc[t][hf][qf][g * 4 + 0] + bb.x, 0.f);
                        float a1 = fmaxf(acc[t][hf][qf][g * 4 + 1] + bb.y, 0.f);
                        float a2 = fmaxf(acc[t][hf][qf][g * 4 + 2] + bb.z, 0.f);
                        float a3 = fmaxf(acc[t][hf][qf][g * 4 + 3] + bb.w, 0.f);
                        uint2 pk;
                        pk.x = cvt_pk(a0, a1);
                        pk.y = cvt_pk(a2, a3);
                        int off = q * 1024 + ((h * 2) ^ ((q & 15) << 4));
                        *(uint2*)(&T[t][off]) = pk;
                    }
                }
            }
        }
    }
    __syncthreads();   // h1 complete

    // ---- GEMM2 (normal): acc2[t][rf][cf] = D2[q, h2] ----
    f32x16 acc2[2][2][2];
#pragma unroll
    for (int t = 0; t < 2; ++t)
#pragma unroll
        for (int i = 0; i < 2; ++i)
#pragma unroll
            for (int j = 0; j < 2; ++j) acc2[t][i][j] = (f32x16)0.f;

    __builtin_amdgcn_s_setprio(1);
#pragma unroll 2
    for (int ks = 0; ks < 32; ++ks) {
        int achunk = (ks * 32 + lg * 16) ^ swz;
        short8 a00 = *(const short8*)(&T[0][arow0 + achunk]);
        short8 a01 = *(const short8*)(&T[0][arow1 + achunk]);
        short8 a10 = *(const short8*)(&T[1][arow0 + achunk]);
        short8 a11 = *(const short8*)(&T[1][arow1 + achunk]);
        const unsigned short* bp = W2s + ((size_t)((ks * 2 + lg) * 512 + wcol + l31)) * 8;
        short8 bv0 = *(const short8*)(bp);
        short8 bv1 = *(const short8*)(bp + 32 * 8);
        acc2[0][0][0] = __builtin_amdgcn_mfma_f32_32x32x16_bf16(a00, bv0, acc2[0][0][0], 0, 0, 0);
        acc2[0][1][0] = __builtin_amdgcn_mfma_f32_32x32x16_bf16(a01, bv0, acc2[0][1][0], 0, 0, 0);
        acc2[0][0][1] = __builtin_amdgcn_mfma_f32_32x32x16_bf16(a00, bv1, acc2[0][0][1], 0, 0, 0);
        acc2[0][1][1] = __builtin_amdgcn_mfma_f32_32x32x16_bf16(a01, bv1, acc2[0][1][1], 0, 0, 0);
        acc2[1][0][0] = __builtin_amdgcn_mfma_f32_32x32x16_bf16(a10, bv0, acc2[1][0][0], 0, 0, 0);
        acc2[1][1][0] = __builtin_amdgcn_mfma_f32_32x32x16_bf16(a11, bv0, acc2[1][1][0], 0, 0, 0);
        acc2[1][0][1] = __builtin_amdgcn_mfma_f32_32x32x16_bf16(a10, bv1, acc2[1][0][1], 0, 0, 0);
        acc2[1][1][1] = __builtin_amdgcn_mfma_f32_32x32x16_bf16(a11, bv1, acc2[1][1][1], 0, 0, 0);
    }
    __builtin_amdgcn_s_setprio(0);

    // ---- relations = relu(acc2 + b2); column-sum over 128 pair-rows ----
    {
        float s[2];
#pragma unroll
        for (int cf = 0; cf < 2; ++cf) {
            int col = wcol + cf * 32 + l31;
            float bias = b2[col];
            float tt = 0.f;
#pragma unroll
            for (int t = 0; t < 2; ++t)
#pragma unroll
                for (int rf = 0; rf < 2; ++rf)
#pragma unroll
                    for (int reg = 0; reg < 16; ++reg)
                        tt += fmaxf(acc2[t][rf][cf][reg] + bias, 0.f);
            tt += __shfl_xor(tt, 32);
            s[cf] = tt;
        }
        if (lane < 32) {
            unsafeAtomicAdd(&emb[b * 512 + wcol + lane], s[0]);
            unsafeAtomicAdd(&emb[b * 512 + wcol + 32 + lane], s[1]);
        }
    }
}

// ---------------------------------------------------------------------------
// Kernel 4: hs = relu(emb @ fW0 + fb0). 256 blocks = (b, 8 slices of 64 cols).
// ---------------------------------------------------------------------------
__global__ __launch_bounds__(256) void f0_kernel(
    const float* __restrict__ emb, const float* __restrict__ fW0,
    const float* __restrict__ fb0, float* __restrict__ hs)
{
    __shared__ float es[512];
    __shared__ float red[256];
    const int b = blockIdx.x >> 3, s = blockIdx.x & 7;
    const int t = threadIdx.x;
    const int colL = t & 63, cg = t >> 6;
    es[t] = emb[b * 512 + t];
    es[t + 256] = emb[b * 512 + 256 + t];
    __syncthreads();
    const int col = s * 64 + colL;
    float a = 0.f;
    const int c0 = cg * 128;
#pragma unroll 4
    for (int c = c0; c < c0 + 128; ++c)
        a += es[c] * fW0[(size_t)c * 512 + col];
    red[t] = a;
    __syncthreads();
    if (t < 64) {
        float r = red[t] + red[t + 64] + red[t + 128] + red[t + 192] + fb0[col];
        hs[b * 512 + col] = fmaxf(r, 0.f);
    }
}

// ---------------------------------------------------------------------------
// Kernel 5: out = hs @ fW1 + fb1. 128 blocks = (b, 4 slices of 64 cols).
// ---------------------------------------------------------------------------
__global__ __launch_bounds__(256) void f1_kernel(
    const float* __restrict__ hs, const float* __restrict__ fW1,
    const float* __restrict__ fb1, float* __restrict__ out)
{
    __shared__ float es[512];
    __shared__ float red[256];
    const int b = blockIdx.x >> 2, s = blockIdx.x & 3;
    const int t = threadIdx.x;
    const int colL = t & 63, cg = t >> 6;
    es[t] = hs[b * 512 + t];
    es[t + 256] = hs[b * 512 + 256 + t];
    __syncthreads();
    const int col = s * 64 + colL;
    float a = 0.f;
    const int c0 = cg * 128;
#pragma unroll 4
    for (int c = c0; c < c0 + 128; ++c)
        a += es[c] * fW1[(size_t)c * 256 + col];
    red[t] = a;
    __syncthreads();
    if (t < 64) {
        out[b * 256 + col] = red[t] + red[t + 64] + red[t + 128] + red[t + 192] + fb1[col];
    }
}

// ---------------------------------------------------------------------------
extern "C" void kernel_launch(void* const* d_in, const int* in_sizes, int n_in,
                              void* d_out, int out_size, void* d_ws, size_t ws_size,
                              hipStream_t stream)
{
    const float* x   = (const float*)d_in[0];
    const float* gW0 = (const float*)d_in[1];
    const float* gb0 = (const float*)d_in[2];
    const float* gW1 = (const float*)d_in[3];
    const float* gb1 = (const float*)d_in[4];
    const float* gW2 = (const float*)d_in[5];
    const float* gb2 = (const float*)d_in[6];
    const float* fW0 = (const float*)d_in[7];
    const float* fb0 = (const float*)d_in[8];
    const float* fW1 = (const float*)d_in[9];
    const float* fb1 = (const float*)d_in[10];
    float* out = (float*)d_out;

    char* ws = (char*)d_ws;
    float* Up           = (float*)(ws);                                   // 4 MB
    float* Vp           = (float*)(ws + (4 << 20));                       // 4 MB
    unsigned short* W1s = (unsigned short*)(ws + (8 << 20));              // 512 KB
    unsigned short* W2s = (unsigned short*)(ws + (8 << 20) + (512 << 10));// 512 KB
    float* emb          = (float*)(ws + (9 << 20));                       // 64 KB
    float* hs           = (float*)(ws + (9 << 20) + (64 << 10));          // 64 KB

    uv_kernel<<<256, 512, 0, stream>>>(x, gW0, gb0, Up, Vp);
    wswz_kernel<<<256, 256, 0, stream>>>(gW1, gW2, W1s, W2s, emb);
    main_kernel<<<1024, 512, 131072, stream>>>(Up, Vp, W1s, W2s, gb1, gb2, emb);
    f0_kernel<<<256, 256, 0, stream>>>(emb, fW0, fb0, hs);
    f1_kernel<<<128, 256, 0, stream>>>(hs, fW1, fb1, out);
}

// Round 4
// 172.137 us; speedup vs baseline: 1.2627x; 1.0327x over previous
//
#include <hip/hip_runtime.h>

// ---------------------------------------------------------------------------
// RelationNetwork: B=32, C=256, N=64 (8x8), D_G_IN=514, HG=HF=512, D_OUT=256
//
//   h0[b,p,q,h] = relu( U'[b,q,h] + V'[b,p,h] )      (layer0 linear in concat)
//   Block = (b, p-pair): builds TWO 64x512 h0 tiles, runs both through
//   GEMM1/GEMM2 sharing each weight fragment across 8 MFMAs. Column sums ->
//   atomicAdd emb. f-MLP as two wide GEMV kernels.
//   r4: batched build loads (all 16 up-front) + depth-2 weight prefetch in
//   fully-unrolled GEMM loops (cover ~300cyc L2 latency with 2 waves/SIMD).
// ---------------------------------------------------------------------------

typedef short short8 __attribute__((ext_vector_type(8)));
typedef float f32x16 __attribute__((ext_vector_type(16)));

__device__ __forceinline__ unsigned short f2bf(float f) {
    unsigned u = __builtin_bit_cast(unsigned, f);
    u = (u + 0x7FFFu + ((u >> 16) & 1u)) >> 16;   // RNE
    return (unsigned short)u;
}

__device__ __forceinline__ unsigned cvt_pk(float a, float b) {
    unsigned r;
    asm("v_cvt_pk_bf16_f32 %0, %1, %2" : "=v"(r) : "v"(a), "v"(b));
    return r;
}

// ---------------------------------------------------------------------------
// Kernel 1: per-object linear terms U', V'
// ---------------------------------------------------------------------------
__global__ __launch_bounds__(512) void uv_kernel(
    const float* __restrict__ x, const float* __restrict__ W0,
    const float* __restrict__ b0, float* __restrict__ Up, float* __restrict__ Vp)
{
    __shared__ float xs[256 * 8];
    const int blk = blockIdx.x;
    const int b = blk >> 3, n0 = (blk & 7) * 8;
    const int tid = threadIdx.x;

    for (int i = tid; i < 2048; i += 512) {
        int c = i >> 3, r = i & 7;
        xs[i] = x[((size_t)b * 256 + c) * 64 + n0 + r];
    }
    __syncthreads();

    const int h = tid;
    float ua[8], va[8];
#pragma unroll
    for (int r = 0; r < 8; ++r) { ua[r] = 0.f; va[r] = 0.f; }

#pragma unroll 4
    for (int c = 0; c < 256; ++c) {
        float wa = W0[(size_t)c * 512 + h];
        float wb = W0[(size_t)(256 + c) * 512 + h];
#pragma unroll
        for (int r = 0; r < 8; ++r) {
            float xv = xs[c * 8 + r];
            ua[r] += xv * wa;
            va[r] += xv * wb;
        }
    }
    const float w2a = W0[(size_t)512 * 512 + h];
    const float w2b = W0[(size_t)513 * 512 + h];
    const float bb = b0[h];
#pragma unroll
    for (int r = 0; r < 8; ++r) {
        int n = n0 + r;
        float fh = (float)(n >> 3), fw = (float)(n & 7);
        Up[((size_t)b * 64 + n) * 512 + h] = ua[r] - fh * w2a - fw * w2b;
        Vp[((size_t)b * 64 + n) * 512 + h] = va[r] + fh * w2a + fw * w2b + bb;
    }
}

// ---------------------------------------------------------------------------
// Kernel 2: W1,W2 -> bf16 fragment order (kg*512+col, 8 k's per chunk),
// plus zero emb (graph-safe re-init every call; runs before main_kernel).
// ---------------------------------------------------------------------------
__global__ __launch_bounds__(256) void wswz_kernel(
    const float* __restrict__ W1, const float* __restrict__ W2,
    unsigned short* __restrict__ W1s, unsigned short* __restrict__ W2s,
    float* __restrict__ emb)
{
    int gid = blockIdx.x * 256 + threadIdx.x;
    if (gid < 16384) emb[gid] = 0.f;
    int m = gid >> 15;
    int idx = gid & 32767;            // kg*512 + col
    int col = idx & 511;
    int kg = idx >> 9;                // 0..63
    const float* W = m ? W2 : W1;
    unsigned short* O = m ? W2s : W1s;
    short8 v;
#pragma unroll
    for (int j = 0; j < 8; ++j)
        v[j] = (short)f2bf(W[(size_t)(kg * 8 + j) * 512 + col]);
    *(short8*)(O + (size_t)idx * 8) = v;
}

// ---------------------------------------------------------------------------
// Kernel 3: fused main kernel, TWO p-tiles per block.
// 1024 blocks = (b, pp) via chunked XCD swizzle (4 b's per XCD -> Up L2-hot);
// 512 threads = 8 waves; wave w owns h-cols [w*64, w*64+64) for BOTH tiles.
// Dynamic LDS 128KB: T0 [64][512] bf16 swizzled + T1. Swizzle: byte ^= (q&15)<<4.
// ---------------------------------------------------------------------------
__global__ __launch_bounds__(512, 2) void main_kernel(
    const float* __restrict__ Up, const float* __restrict__ Vp,
    const unsigned short* __restrict__ W1s, const unsigned short* __restrict__ W2s,
    const float* __restrict__ b1, const float* __restrict__ b2,
    float* __restrict__ emb)
{
    extern __shared__ __align__(16) unsigned char lds[];
    unsigned char* T0 = lds;
    unsigned char* T1 = lds + 65536;

    // chunked bijective XCD swizzle: 1024 wgs, 128 per XCD
    const int wg = ((blockIdx.x & 7) << 7) | (blockIdx.x >> 3);
    const int b = wg >> 5, pp = wg & 31;
    const int p0 = pp * 2, p1 = p0 + 1;

    const int tid = threadIdx.x;
    const int lane = tid & 63, wave = tid >> 6;
    const int l31 = lane & 31, lg = lane >> 5;
    const int swz = (l31 & 15) << 4;
    const int wcol = wave * 64;

    // ---- build h0 tiles: issue ALL global loads first, then compute ----
    {
        const int cc = tid & 63;            // col-chunk of 8 (== lane)
        const int r0 = tid >> 6;            // == wave
        float4 u0[8], u1[8];
#pragma unroll
        for (int it = 0; it < 8; ++it) {
            const float* ub = Up + ((size_t)(b * 64 + r0 + it * 8)) * 512 + cc * 8;
            u0[it] = *(const float4*)(ub);
            u1[it] = *(const float4*)(ub + 4);
        }
        const float* vA = Vp + ((size_t)(b * 64 + p0)) * 512 + cc * 8;
        const float* vB = Vp + ((size_t)(b * 64 + p1)) * 512 + cc * 8;
        float4 vA0 = *(const float4*)(vA), vA1 = *(const float4*)(vA + 4);
        float4 vB0 = *(const float4*)(vB), vB1 = *(const float4*)(vB + 4);
#pragma unroll
        for (int it = 0; it < 8; ++it) {
            int row = r0 + it * 8;          // q
            int off = row * 1024 + ((cc * 16) ^ ((row & 15) << 4));
            uint4 w;
            w.x = cvt_pk(fmaxf(u0[it].x + vA0.x, 0.f), fmaxf(u0[it].y + vA0.y, 0.f));
            w.y = cvt_pk(fmaxf(u0[it].z + vA0.z, 0.f), fmaxf(u0[it].w + vA0.w, 0.f));
            w.z = cvt_pk(fmaxf(u1[it].x + vA1.x, 0.f), fmaxf(u1[it].y + vA1.y, 0.f));
            w.w = cvt_pk(fmaxf(u1[it].z + vA1.z, 0.f), fmaxf(u1[it].w + vA1.w, 0.f));
            *(uint4*)(&T0[off]) = w;
            w.x = cvt_pk(fmaxf(u0[it].x + vB0.x, 0.f), fmaxf(u0[it].y + vB0.y, 0.f));
            w.y = cvt_pk(fmaxf(u0[it].z + vB0.z, 0.f), fmaxf(u0[it].w + vB0.w, 0.f));
            w.z = cvt_pk(fmaxf(u1[it].x + vB1.x, 0.f), fmaxf(u1[it].y + vB1.y, 0.f));
            w.w = cvt_pk(fmaxf(u1[it].z + vB1.z, 0.f), fmaxf(u1[it].w + vB1.w, 0.f));
            *(uint4*)(&T1[off]) = w;
        }
    }
    __syncthreads();

    const int arow0 = l31 * 1024;
    const int arow1 = (l31 + 32) * 1024;

    // ---- GEMM1 (swapped): acc[t][hf][qf] = D1[h, q]; depth-2 W prefetch ----
    f32x16 acc[2][2][2];
#pragma unroll
    for (int t = 0; t < 2; ++t)
#pragma unroll
        for (int i = 0; i < 2; ++i)
#pragma unroll
            for (int j = 0; j < 2; ++j) acc[t][i][j] = (f32x16)0.f;

    {
        const unsigned short* wb = W1s + ((size_t)(lg * 512 + wcol + l31)) * 8;
        short8 wc0[2], wc1[2];
        wc0[0] = *(const short8*)(wb);
        wc1[0] = *(const short8*)(wb + 256);
        wc0[1] = *(const short8*)(wb + 8192);
        wc1[1] = *(const short8*)(wb + 8192 + 256);
        __builtin_amdgcn_s_setprio(1);
#pragma unroll
        for (int ks = 0; ks < 32; ++ks) {
            const int par = ks & 1;
            short8 cw0 = wc0[par], cw1 = wc1[par];
            if (ks < 30) {
                const unsigned short* np = wb + (size_t)(ks + 2) * 8192;
                wc0[par] = *(const short8*)(np);
                wc1[par] = *(const short8*)(np + 256);
            }
            int achunk = (ks * 32 + lg * 16) ^ swz;
            short8 a00 = *(const short8*)(&T0[arow0 + achunk]);
            short8 a01 = *(const short8*)(&T0[arow1 + achunk]);
            short8 a10 = *(const short8*)(&T1[arow0 + achunk]);
            short8 a11 = *(const short8*)(&T1[arow1 + achunk]);
            acc[0][0][0] = __builtin_amdgcn_mfma_f32_32x32x16_bf16(cw0, a00, acc[0][0][0], 0, 0, 0);
            acc[0][1][0] = __builtin_amdgcn_mfma_f32_32x32x16_bf16(cw1, a00, acc[0][1][0], 0, 0, 0);
            acc[0][0][1] = __builtin_amdgcn_mfma_f32_32x32x16_bf16(cw0, a01, acc[0][0][1], 0, 0, 0);
            acc[0][1][1] = __builtin_amdgcn_mfma_f32_32x32x16_bf16(cw1, a01, acc[0][1][1], 0, 0, 0);
            acc[1][0][0] = __builtin_amdgcn_mfma_f32_32x32x16_bf16(cw0, a10, acc[1][0][0], 0, 0, 0);
            acc[1][1][0] = __builtin_amdgcn_mfma_f32_32x32x16_bf16(cw1, a10, acc[1][1][0], 0, 0, 0);
            acc[1][0][1] = __builtin_amdgcn_mfma_f32_32x32x16_bf16(cw0, a11, acc[1][0][1], 0, 0, 0);
            acc[1][1][1] = __builtin_amdgcn_mfma_f32_32x32x16_bf16(cw1, a11, acc[1][1][1], 0, 0, 0);
        }
        __builtin_amdgcn_s_setprio(0);
    }
    __syncthreads();   // all waves done READING h0

    // ---- h1 = relu(acc + b1) -> bf16 back into T0/T1 ----
    // acc[t][hf][qf] reg r: h = wcol + hf*32 + (r&3) + 8*(r>>2) + 4*lg, q = qf*32 + l31
    {
#pragma unroll
        for (int hf = 0; hf < 2; ++hf) {
#pragma unroll
            for (int g = 0; g < 4; ++g) {
                int h = wcol + hf * 32 + g * 8 + 4 * lg;
                float4 bb = *(const float4*)(b1 + h);
#pragma unroll
                for (int t = 0; t < 2; ++t) {
#pragma unroll
                    for (int qf = 0; qf < 2; ++qf) {
                        int q = qf * 32 + l31;
                        float a0 = fmaxf(acc[t][hf][qf][g * 4 + 0] + bb.x, 0.f);
                        float a1 = fmaxf(acc[t][hf][qf][g * 4 + 1] + bb.y, 0.f);
                        float a2 = fmaxf(acc[t][hf][qf][g * 4 + 2] + bb.z, 0.f);
                        float a3 = fmaxf(acc[t][hf][qf][g * 4 + 3] + bb.w, 0.f);
                        uint2 pk;
                        pk.x = cvt_pk(a0, a1);
                        pk.y = cvt_pk(a2, a3);
                        int off = q * 1024 + ((h * 2) ^ ((q & 15) << 4));
                        unsigned char* Tt = t ? T1 : T0;
                        *(uint2*)(&Tt[off]) = pk;
                    }
                }
            }
        }
    }
    __syncthreads();   // h1 complete

    // ---- GEMM2 (normal): acc2[t][rf][cf] = D2[q, h2]; depth-2 W prefetch ----
    f32x16 acc2[2][2][2];
#pragma unroll
    for (int t = 0; t < 2; ++t)
#pragma unroll
        for (int i = 0; i < 2; ++i)
#pragma unroll
            for (int j = 0; j < 2; ++j) acc2[t][i][j] = (f32x16)0.f;

    {
        const unsigned short* wb = W2s + ((size_t)(lg * 512 + wcol + l31)) * 8;
        short8 wc0[2], wc1[2];
        wc0[0] = *(const short8*)(wb);
        wc1[0] = *(const short8*)(wb + 256);
        wc0[1] = *(const short8*)(wb + 8192);
        wc1[1] = *(const short8*)(wb + 8192 + 256);
        __builtin_amdgcn_s_setprio(1);
#pragma unroll
        for (int ks = 0; ks < 32; ++ks) {
            const int par = ks & 1;
            short8 cw0 = wc0[par], cw1 = wc1[par];
            if (ks < 30) {
                const unsigned short* np = wb + (size_t)(ks + 2) * 8192;
                wc0[par] = *(const short8*)(np);
                wc1[par] = *(const short8*)(np + 256);
            }
            int achunk = (ks * 32 + lg * 16) ^ swz;
            short8 a00 = *(const short8*)(&T0[arow0 + achunk]);
            short8 a01 = *(const short8*)(&T0[arow1 + achunk]);
            short8 a10 = *(const short8*)(&T1[arow0 + achunk]);
            short8 a11 = *(const short8*)(&T1[arow1 + achunk]);
            acc2[0][0][0] = __builtin_amdgcn_mfma_f32_32x32x16_bf16(a00, cw0, acc2[0][0][0], 0, 0, 0);
            acc2[0][1][0] = __builtin_amdgcn_mfma_f32_32x32x16_bf16(a01, cw0, acc2[0][1][0], 0, 0, 0);
            acc2[0][0][1] = __builtin_amdgcn_mfma_f32_32x32x16_bf16(a00, cw1, acc2[0][0][1], 0, 0, 0);
            acc2[0][1][1] = __builtin_amdgcn_mfma_f32_32x32x16_bf16(a01, cw1, acc2[0][1][1], 0, 0, 0);
            acc2[1][0][0] = __builtin_amdgcn_mfma_f32_32x32x16_bf16(a10, cw0, acc2[1][0][0], 0, 0, 0);
            acc2[1][1][0] = __builtin_amdgcn_mfma_f32_32x32x16_bf16(a11, cw0, acc2[1][1][0], 0, 0, 0);
            acc2[1][0][1] = __builtin_amdgcn_mfma_f32_32x32x16_bf16(a10, cw1, acc2[1][0][1], 0, 0, 0);
            acc2[1][1][1] = __builtin_amdgcn_mfma_f32_32x32x16_bf16(a11, cw1, acc2[1][1][1], 0, 0, 0);
        }
        __builtin_amdgcn_s_setprio(0);
    }

    // ---- relations = relu(acc2 + b2); column-sum over 128 pair-rows ----
    {
        float s[2];
#pragma unroll
        for (int cf = 0; cf < 2; ++cf) {
            int col = wcol + cf * 32 + l31;
            float bias = b2[col];
            float tt = 0.f;
#pragma unroll
            for (int t = 0; t < 2; ++t)
#pragma unroll
                for (int rf = 0; rf < 2; ++rf)
#pragma unroll
                    for (int reg = 0; reg < 16; ++reg)
                        tt += fmaxf(acc2[t][rf][cf][reg] + bias, 0.f);
            tt += __shfl_xor(tt, 32);
            s[cf] = tt;
        }
        if (lane < 32) {
            unsafeAtomicAdd(&emb[b * 512 + wcol + lane], s[0]);
            unsafeAtomicAdd(&emb[b * 512 + wcol + 32 + lane], s[1]);
        }
    }
}

// ---------------------------------------------------------------------------
// Kernel 4: hs = relu(emb @ fW0 + fb0). 256 blocks = (b, 8 slices of 64 cols).
// ---------------------------------------------------------------------------
__global__ __launch_bounds__(256) void f0_kernel(
    const float* __restrict__ emb, const float* __restrict__ fW0,
    const float* __restrict__ fb0, float* __restrict__ hs)
{
    __shared__ float es[512];
    __shared__ float red[256];
    const int b = blockIdx.x >> 3, s = blockIdx.x & 7;
    const int t = threadIdx.x;
    const int colL = t & 63, cg = t >> 6;
    es[t] = emb[b * 512 + t];
    es[t + 256] = emb[b * 512 + 256 + t];
    __syncthreads();
    const int col = s * 64 + colL;
    float a = 0.f;
    const int c0 = cg * 128;
#pragma unroll 4
    for (int c = c0; c < c0 + 128; ++c)
        a += es[c] * fW0[(size_t)c * 512 + col];
    red[t] = a;
    __syncthreads();
    if (t < 64) {
        float r = red[t] + red[t + 64] + red[t + 128] + red[t + 192] + fb0[col];
        hs[b * 512 + col] = fmaxf(r, 0.f);
    }
}

// ---------------------------------------------------------------------------
// Kernel 5: out = hs @ fW1 + fb1. 128 blocks = (b, 4 slices of 64 cols).
// ---------------------------------------------------------------------------
__global__ __launch_bounds__(256) void f1_kernel(
    const float* __restrict__ hs, const float* __restrict__ fW1,
    const float* __restrict__ fb1, float* __restrict__ out)
{
    __shared__ float es[512];
    __shared__ float red[256];
    const int b = blockIdx.x >> 2, s = blockIdx.x & 3;
    const int t = threadIdx.x;
    const int colL = t & 63, cg = t >> 6;
    es[t] = hs[b * 512 + t];
    es[t + 256] = hs[b * 512 + 256 + t];
    __syncthreads();
    const int col = s * 64 + colL;
    float a = 0.f;
    const int c0 = cg * 128;
#pragma unroll 4
    for (int c = c0; c < c0 + 128; ++c)
        a += es[c] * fW1[(size_t)c * 256 + col];
    red[t] = a;
    __syncthreads();
    if (t < 64) {
        out[b * 256 + col] = red[t] + red[t + 64] + red[t + 128] + red[t + 192] + fb1[col];
    }
}

// ---------------------------------------------------------------------------
extern "C" void kernel_launch(void* const* d_in, const int* in_sizes, int n_in,
                              void* d_out, int out_size, void* d_ws, size_t ws_size,
                              hipStream_t stream)
{
    const float* x   = (const float*)d_in[0];
    const float* gW0 = (const float*)d_in[1];
    const float* gb0 = (const float*)d_in[2];
    const float* gW1 = (const float*)d_in[3];
    const float* gb1 = (const float*)d_in[4];
    const float* gW2 = (const float*)d_in[5];
    const float* gb2 = (const float*)d_in[6];
    const float* fW0 = (const float*)d_in[7];
    const float* fb0 = (const float*)d_in[8];
    const float* fW1 = (const float*)d_in[9];
    const float* fb1 = (const float*)d_in[10];
    float* out = (float*)d_out;

    char* ws = (char*)d_ws;
    float* Up           = (float*)(ws);                                   // 4 MB
    float* Vp           = (float*)(ws + (4 << 20));                       // 4 MB
    unsigned short* W1s = (unsigned short*)(ws + (8 << 20));              // 512 KB
    unsigned short* W2s = (unsigned short*)(ws + (8 << 20) + (512 << 10));// 512 KB
    float* emb          = (float*)(ws + (9 << 20));                       // 64 KB
    float* hs           = (float*)(ws + (9 << 20) + (64 << 10));          // 64 KB

    uv_kernel<<<256, 512, 0, stream>>>(x, gW0, gb0, Up, Vp);
    wswz_kernel<<<256, 256, 0, stream>>>(gW1, gW2, W1s, W2s, emb);
    main_kernel<<<1024, 512, 131072, stream>>>(Up, Vp, W1s, W2s, gb1, gb2, emb);
    f0_kernel<<<256, 256, 0, stream>>>(emb, fW0, fb0, hs);
    f1_kernel<<<128, 256, 0, stream>>>(hs, fW1, fb1, out);
}